// Round 4
// baseline (606.130 us; speedup 1.0000x reference)
//
#include <hip/hip_runtime.h>
#include <hip/hip_bf16.h>
#include <stdint.h>

#define N_OBS 65536
#define N_DIM 256
#define N_FUN 16
#define N_APP 8
#define MT 64
#define N_BLK 256

typedef __attribute__((ext_vector_type(8))) short v8s;
typedef __attribute__((ext_vector_type(4))) short v4s;
typedef __attribute__((ext_vector_type(4))) float v4f;

__device__ __forceinline__ unsigned short f2bf(float f) {
  union { float f; uint32_t u; } v;
  v.f = f;
  uint32_t u = v.u;
  return (unsigned short)((u + 0x7FFFu + ((u >> 16) & 1u)) >> 16);
}

// bijective XCD swizzle (grid % 8 == 0): consecutive tiles -> same XCD L2
__device__ __forceinline__ int xcd_swz(int bid, int n) {
  int q = n >> 3;
  return (bid & 7) * q + (bid >> 3);
}

__global__ void k_init(int* __restrict__ perm, int total) {
  int tid = blockIdx.x * 256 + threadIdx.x;
  if (tid < total) perm[tid] = -1;
}

// W (f,d,e) f32 -> Wt (f,e,d) bf16
__global__ void k_prep_w(const float* __restrict__ W, unsigned short* __restrict__ Wt) {
  int tid = blockIdx.x * 256 + threadIdx.x;
  int f = tid >> 16, n = (tid >> 8) & 255, k = tid & 255;
  Wt[tid] = f2bf(W[(f << 16) | (k << 8) | n]);
}

// per-block histogram; pairMode: bins = 4 steps x 256 pairs, else 8 x 16
__global__ void k_hist(const int* __restrict__ fidx, int* __restrict__ blockCnt,
                       int pairMode) {
  __shared__ int h[1024];
  int nb = pairMode ? 1024 : 128;
  int tid = threadIdx.x;
  for (int j = tid; j < nb; j += 256) h[j] = 0;
  __syncthreads();
  size_t o = blockIdx.x * 256 + tid;
  const int4* p = (const int4*)(fidx + o * 8);
  int4 a = p[0], b = p[1];
  int fs[8] = {a.x, a.y, a.z, a.w, b.x, b.y, b.z, b.w};
  if (pairMode) {
    #pragma unroll
    for (int t = 0; t < 4; ++t)
      atomicAdd(&h[t * 256 + fs[2 * t] * 16 + fs[2 * t + 1]], 1);
  } else {
    #pragma unroll
    for (int t = 0; t < 8; ++t) atomicAdd(&h[t * 16 + fs[t]], 1);
  }
  __syncthreads();
  for (int j = tid; j < nb; j += 256) blockCnt[j * N_BLK + blockIdx.x] = h[j];
}

// totals -> padded bases -> per-block offsets; tile->f map
__global__ void k_scan(const int* __restrict__ blockCnt, int* __restrict__ pb,
                       int* __restrict__ tilef, int* __restrict__ blockOff,
                       int ns, int ng, int maxt) {
  __shared__ int tot[1024];
  int i = threadIdx.x;
  int nb = ns * ng;
  if (i < nb) {
    int s = 0;
    for (int b = 0; b < N_BLK; ++b) s += blockCnt[i * N_BLK + b];
    tot[i] = s;
  }
  __syncthreads();
  if (i < ns) {
    int base = 0;
    for (int f = 0; f < ng; ++f) {
      pb[i * (ng + 1) + f] = base;
      int c = tot[i * ng + f];
      int padded = (c + MT - 1) & ~(MT - 1);
      int q1 = (base + padded) >> 6;
      for (int q = base >> 6; q < q1; ++q) tilef[i * maxt + q] = f;
      base += padded;
    }
    pb[i * (ng + 1) + ng] = base;
  }
  __syncthreads();
  if (i < nb) {
    int t = i / ng, f = i - t * ng;
    int off = pb[t * (ng + 1) + f];
    for (int b = 0; b < N_BLK; ++b) {
      blockOff[i * N_BLK + b] = off;
      off += blockCnt[i * N_BLK + b];
    }
  }
}

__global__ void k_scatter(const int* __restrict__ fidx, const int* __restrict__ blockOff,
                          int* __restrict__ perm, int pairMode, int stride) {
  __shared__ int cur[1024];
  int nb = pairMode ? 1024 : 128;
  int tid = threadIdx.x;
  for (int j = tid; j < nb; j += 256) cur[j] = blockOff[j * N_BLK + blockIdx.x];
  __syncthreads();
  size_t o = blockIdx.x * 256 + tid;
  const int4* p = (const int4*)(fidx + o * 8);
  int4 a = p[0], b = p[1];
  int fs[8] = {a.x, a.y, a.z, a.w, b.x, b.y, b.z, b.w};
  if (pairMode) {
    #pragma unroll
    for (int t = 0; t < 4; ++t) {
      int pos = atomicAdd(&cur[t * 256 + fs[2 * t] * 16 + fs[2 * t + 1]], 1);
      perm[t * stride + pos] = (int)o;
    }
  } else {
    #pragma unroll
    for (int t = 0; t < 8; ++t) {
      int pos = atomicAdd(&cur[t * 16 + fs[t]], 1);
      perm[t * stride + pos] = (int)o;
    }
  }
}

// pos_t[o] = slot of row o in layout t (t=1..ns-1)
__global__ void k_pos(const int* __restrict__ perm, int* __restrict__ pos,
                      int stride, int total) {
  int tid = blockIdx.x * 256 + threadIdx.x;
  if (tid >= total) return;
  int t = tid / stride + 1, s = tid - (t - 1) * stride;
  int o = perm[t * stride + s];
  if (o >= 0) pos[(t - 1) * N_OBS + o] = s;
}

// outpos[t][s] = pos_{t+1}[perm[t][s]] (t=0..ns-2); in-place for t>=1
__global__ void k_outpos(int* __restrict__ perm, const int* __restrict__ pos,
                         int* __restrict__ outpos0, int stride, int total) {
  int tid = blockIdx.x * 256 + threadIdx.x;
  if (tid >= total) return;
  int t = tid / stride, s = tid - t * stride;
  int o = perm[t * stride + s];
  int val = (o >= 0) ? pos[t * N_OBS + o] : -1;
  if (t == 0) outpos0[s] = val;
  else perm[t * stride + s] = val;
}

// composed bias: bc[pair][e] = sum_k b[f][k]*W[g][k][e] + b[g][e]  (f=pair>>4,g=pair&15)
__global__ void k_biasc(const float* __restrict__ W, const float* __restrict__ b,
                        float* __restrict__ bc) {
  int pair = blockIdx.x, e = threadIdx.x;
  int f = pair >> 4, g = pair & 15;
  const float* Wg = W + ((size_t)g << 16);
  const float* bf_ = b + (f << 8);
  float acc = b[(g << 8) + e];
  for (int k = 0; k < 256; ++k) acc += bf_[k] * Wg[(k << 8) + e];
  bc[(pair << 8) + e] = acc;
}

// composed matrix: Wc[pair][e][d] = sum_k W[f][d][k]*W[g][k][e], bf16, f32 accum
__global__ __launch_bounds__(256, 5)
void k_compose(const float* __restrict__ W, const unsigned short* __restrict__ Wt,
               unsigned short* __restrict__ Wc) {
  __shared__ unsigned short As[MT * N_DIM];   // 32 KB
  int bid = xcd_swz(blockIdx.x, gridDim.x);
  int pair = bid >> 2, dt = bid & 3;
  int f = pair >> 4, g = pair & 15;
  int tid = threadIdx.x;
  // stage A = W[f][dt*64+row][k] (f32->bf16), swizzled
  #pragma unroll
  for (int i = 0; i < 8; ++i) {
    int g0 = tid + i * 256;
    int row = g0 >> 5, c = g0 & 31;
    const v4f* s = (const v4f*)(W + ((size_t)f << 16) + ((dt * 64 + row) << 8) + (c << 3));
    v4f v0 = s[0], v1 = s[1];
    v8s val;
    val[0] = (short)f2bf(v0[0]); val[1] = (short)f2bf(v0[1]);
    val[2] = (short)f2bf(v0[2]); val[3] = (short)f2bf(v0[3]);
    val[4] = (short)f2bf(v1[0]); val[5] = (short)f2bf(v1[1]);
    val[6] = (short)f2bf(v1[2]); val[7] = (short)f2bf(v1[3]);
    *(v8s*)((char*)As + (row << 9) + ((c ^ (row & 7)) << 4)) = val;
  }
  __syncthreads();
  int lane = tid & 63, wave = tid >> 6, l15 = lane & 15, lq = lane >> 4;
  v4f acc[4][4] = {};
  const unsigned short* Wg = Wt + ((size_t)g << 16);
  #pragma unroll
  for (int kk = 0; kk < 8; ++kk) {
    v8s a[4];
    #pragma unroll
    for (int mt = 0; mt < 4; ++mt) {
      int row = mt * 16 + l15;
      a[mt] = *(const v8s*)((const char*)As + (row << 9) + ((((kk << 2) + lq) ^ (row & 7)) << 4));
    }
    #pragma unroll
    for (int nt = 0; nt < 4; ++nt) {
      int n = wave * 64 + nt * 16 + l15;
      v8s bfr = *(const v8s*)(Wg + n * N_DIM + (kk << 5) + (lq << 3));
      #pragma unroll
      for (int mt = 0; mt < 4; ++mt)
        // non-swapped: D col(lane&15)=e (bfr row), D row(lq*4+r)=d (a row)
        acc[mt][nt] = __builtin_amdgcn_mfma_f32_16x16x32_bf16(a[mt], bfr, acc[mt][nt], 0, 0, 0);
    }
  }
  __syncthreads();
  // stage C^T tile: CT[e][m], 256 x 64 bf16 (=32 KB), swizzled within 128B rows
  #pragma unroll
  for (int mt = 0; mt < 4; ++mt) {
    #pragma unroll
    for (int nt = 0; nt < 4; ++nt) {
      int e = wave * 64 + nt * 16 + l15;
      int m0 = mt * 16 + lq * 4;
      v4s pk;
      pk[0] = (short)f2bf(acc[mt][nt][0]);
      pk[1] = (short)f2bf(acc[mt][nt][1]);
      pk[2] = (short)f2bf(acc[mt][nt][2]);
      pk[3] = (short)f2bf(acc[mt][nt][3]);
      *(v4s*)((char*)As + (e << 7) + ((m0 << 1) ^ ((e & 7) << 4))) = pk;
    }
  }
  __syncthreads();
  #pragma unroll
  for (int i = 0; i < 8; ++i) {
    int g0 = tid + i * 256;
    int e = g0 >> 3, c = g0 & 7;
    v8s v = *(const v8s*)((char*)As + (e << 7) + (((c << 4) ^ ((e & 7) << 4))));
    *(v8s*)(Wc + ((size_t)pair << 16) + (e << 8) + (dt << 6) + (c << 3)) = v;
  }
}

// one application step (generic over function/pair count ng)
template <int SRC_F32, int DST_F32>
__global__ __launch_bounds__(256, 5)
void k_step(const void* __restrict__ src_, void* __restrict__ dst_,
            const unsigned short* __restrict__ Wmat, const float* __restrict__ bias,
            const int* __restrict__ pb_t, const int* __restrict__ tilef_t,
            const int* __restrict__ outpos_t, const int* __restrict__ perm0, int ng) {
  __shared__ unsigned short As[MT * N_DIM];   // exactly 32768 B -> 5 blocks/CU
  int tile = xcd_swz(blockIdx.x, gridDim.x);
  if (tile * MT >= pb_t[ng]) return;
  int f = tilef_t[tile];
  int tid = threadIdx.x;

  if (SRC_F32) {
    const int* permBase = perm0 + tile * MT;
    #pragma unroll
    for (int i = 0; i < 8; ++i) {
      int g0 = tid + i * 256;
      int row = g0 >> 5, c = g0 & 31;
      int grow = permBase[row];
      if (grow < 0) grow = 0;   // clamp; garbage rows masked at write
      const v4f* s = (const v4f*)((const float*)src_ + ((size_t)grow << 8) + (c << 3));
      v4f v0 = s[0], v1 = s[1];
      v8s val;
      val[0] = (short)f2bf(v0[0]); val[1] = (short)f2bf(v0[1]);
      val[2] = (short)f2bf(v0[2]); val[3] = (short)f2bf(v0[3]);
      val[4] = (short)f2bf(v1[0]); val[5] = (short)f2bf(v1[1]);
      val[6] = (short)f2bf(v1[2]); val[7] = (short)f2bf(v1[3]);
      *(v8s*)((char*)As + (row << 9) + ((c ^ (row & 7)) << 4)) = val;
    }
  } else {
    const unsigned short* srcT = (const unsigned short*)src_ + (size_t)tile * MT * N_DIM;
    #pragma unroll
    for (int i = 0; i < 8; ++i) {
      int g0 = tid + i * 256;
      int row = g0 >> 5, c = g0 & 31;
      v8s val = *(const v8s*)(srcT + (size_t)g0 * 8);
      *(v8s*)((char*)As + (row << 9) + ((c ^ (row & 7)) << 4)) = val;
    }
  }
  __syncthreads();

  int lane = tid & 63, wave = tid >> 6, l15 = lane & 15, lq = lane >> 4;
  v4f acc[4][4] = {};
  const unsigned short* Wf = Wmat + ((size_t)f << 16);

  #pragma unroll
  for (int kk = 0; kk < 8; ++kk) {
    v8s a[4];
    #pragma unroll
    for (int mt = 0; mt < 4; ++mt) {
      int row = mt * 16 + l15;
      a[mt] = *(const v8s*)((const char*)As + (row << 9) + ((((kk << 2) + lq) ^ (row & 7)) << 4));
    }
    #pragma unroll
    for (int nt = 0; nt < 4; ++nt) {
      int n = wave * 64 + nt * 16 + l15;
      v8s bfr = *(const v8s*)(Wf + n * N_DIM + (kk << 5) + (lq << 3));
      #pragma unroll
      for (int mt = 0; mt < 4; ++mt)
        // swapped: lane l15 = row m, lq*4+r = col n
        acc[mt][nt] = __builtin_amdgcn_mfma_f32_16x16x32_bf16(bfr, a[mt], acc[mt][nt], 0, 0, 0);
    }
  }

  const float* bf_ = bias + f * N_DIM;
  if (DST_F32) {
    float* dout = (float*)dst_;
    #pragma unroll
    for (int mt = 0; mt < 4; ++mt) {
      int m = mt * 16 + l15;
      int orow = outpos_t[tile * MT + m];
      if (orow >= 0) {
        #pragma unroll
        for (int nt = 0; nt < 4; ++nt) {
          int n0 = wave * 64 + nt * 16 + lq * 4;
          v4f bv = *(const v4f*)(bf_ + n0);
          v4f o = acc[mt][nt] + bv;
          *(v4f*)(dout + ((size_t)orow << 8) + n0) = o;
        }
      }
    }
  } else {
    __syncthreads();   // reuse As to stage C (bf16)
    #pragma unroll
    for (int mt = 0; mt < 4; ++mt) {
      int m = mt * 16 + l15;
      #pragma unroll
      for (int nt = 0; nt < 4; ++nt) {
        int n0 = wave * 64 + nt * 16 + lq * 4;
        v4f bv = *(const v4f*)(bf_ + n0);
        v4s pk;
        pk[0] = (short)f2bf(acc[mt][nt][0] + bv[0]);
        pk[1] = (short)f2bf(acc[mt][nt][1] + bv[1]);
        pk[2] = (short)f2bf(acc[mt][nt][2] + bv[2]);
        pk[3] = (short)f2bf(acc[mt][nt][3] + bv[3]);
        int c = n0 >> 3;
        *(v4s*)((char*)As + (m << 9) + (((c ^ (m & 7)) << 4)) + ((n0 & 7) << 1)) = pk;
      }
    }
    __syncthreads();
    unsigned short* dst = (unsigned short*)dst_;
    #pragma unroll
    for (int i = 0; i < 8; ++i) {
      int g0 = tid + i * 256;
      int row = g0 >> 5, c = g0 & 31;
      int op = outpos_t[tile * MT + row];
      if (op >= 0) {
        v8s v = *(const v8s*)((char*)As + (row << 9) + ((c ^ (row & 7)) << 4));
        *(v8s*)(dst + (size_t)op * N_DIM + c * 8) = v;
      }
    }
  }
}

extern "C" void kernel_launch(void* const* d_in, const int* in_sizes, int n_in,
                              void* d_out, int out_size, void* d_ws, size_t ws_size,
                              hipStream_t stream) {
  const float* x = (const float*)d_in[0];
  const int* fidx = (const int*)d_in[1];
  const float* W = (const float*)d_in[2];
  const float* bias = (const float*)d_in[3];
  char* ws = (char*)d_ws;

  const size_t NEED_PAIR = 80u * 1024u * 1024u;   // actual use ~79.52 MB
  if (ws_size >= NEED_PAIR) {
    // ---- pair mode: 4 composed steps over 256 pair-functions ----
    const int NS = 4, NG = 256, STRIDE = 81920, MAXT = 1280;
    unsigned short* carryA = (unsigned short*)ws;            // 41,943,040 B
    int* blockCnt = (int*)ws;                                // overlap (dead pre-step0)
    int* blockOff = (int*)(ws + 1048576);
    int* pos      = (int*)(ws + 2097152);                    // 3*N_OBS*4
    unsigned short* Wc = (unsigned short*)(ws + 41943040);   // 33,554,432 B
    unsigned short* Wt = (unsigned short*)(ws + 75497472);   // 2 MB
    float* bc    = (float*)(ws + 77594624);                  // 256 KB
    int* perm    = (int*)(ws + 77856768);                    // 4*81920*4
    int* pb      = (int*)(ws + 79167488);                    // 4*257*4
    int* tilef   = (int*)(ws + 79171600);                    // 4*1280*4
    int* outpos0 = (int*)(ws + 79192080);                    // 81920*4
    unsigned short* carryB = (unsigned short*)d_out;         // 41.9 MB of 64

    k_init<<<(NS * STRIDE + 255) / 256, 256, 0, stream>>>(perm, NS * STRIDE);
    k_prep_w<<<(N_FUN * 65536) / 256, 256, 0, stream>>>(W, Wt);
    k_hist<<<N_BLK, 256, 0, stream>>>(fidx, blockCnt, 1);
    k_scan<<<1, 1024, 0, stream>>>(blockCnt, pb, tilef, blockOff, NS, NG, MAXT);
    k_scatter<<<N_BLK, 256, 0, stream>>>(fidx, blockOff, perm, 1, STRIDE);
    k_pos<<<((NS - 1) * STRIDE + 255) / 256, 256, 0, stream>>>(perm, pos, STRIDE, (NS - 1) * STRIDE);
    k_outpos<<<((NS - 1) * STRIDE + 255) / 256, 256, 0, stream>>>(perm, pos, outpos0, STRIDE, (NS - 1) * STRIDE);
    k_biasc<<<256, 256, 0, stream>>>(W, bias, bc);
    k_compose<<<1024, 256, 0, stream>>>(W, Wt, Wc);

    k_step<1, 0><<<MAXT, 256, 0, stream>>>(x, carryA, Wc, bc, pb, tilef, outpos0, perm, NG);
    k_step<0, 0><<<MAXT, 256, 0, stream>>>(carryA, carryB, Wc, bc,
        pb + 1 * (NG + 1), tilef + 1 * MAXT, perm + 1 * STRIDE, nullptr, NG);
    k_step<0, 0><<<MAXT, 256, 0, stream>>>(carryB, carryA, Wc, bc,
        pb + 2 * (NG + 1), tilef + 2 * MAXT, perm + 2 * STRIDE, nullptr, NG);
    k_step<0, 1><<<MAXT, 256, 0, stream>>>(carryA, d_out, Wc, bc,
        pb + 3 * (NG + 1), tilef + 3 * MAXT, perm + 3 * STRIDE, nullptr, NG);
  } else {
    // ---- fallback: 8 plain steps (proven round-3 pipeline) ----
    const int NS = 8, NG = 16, STRIDE = 66560, MAXT = 1040;
    unsigned short* carryA = (unsigned short*)ws;            // 34,078,720 B
    int* blockCnt = (int*)ws;
    int* blockOff = (int*)(ws + 1048576);
    int* pos      = (int*)(ws + 2097152);                    // 7*N_OBS*4
    unsigned short* Wt = (unsigned short*)(ws + 34078720);   // 2 MB
    int* perm    = (int*)(ws + 36175872);                    // 8*66560*4
    int* pb      = (int*)(ws + 38305792);                    // 8*17*4
    int* tilef   = (int*)(ws + 38306336);                    // 8*1040*4
    int* outpos0 = (int*)(ws + 38339616);                    // 66560*4
    unsigned short* carryB = (unsigned short*)d_out;

    k_init<<<(NS * STRIDE + 255) / 256, 256, 0, stream>>>(perm, NS * STRIDE);
    k_prep_w<<<(N_FUN * 65536) / 256, 256, 0, stream>>>(W, Wt);
    k_hist<<<N_BLK, 256, 0, stream>>>(fidx, blockCnt, 0);
    k_scan<<<1, 1024, 0, stream>>>(blockCnt, pb, tilef, blockOff, NS, NG, MAXT);
    k_scatter<<<N_BLK, 256, 0, stream>>>(fidx, blockOff, perm, 0, STRIDE);
    k_pos<<<((NS - 1) * STRIDE + 255) / 256, 256, 0, stream>>>(perm, pos, STRIDE, (NS - 1) * STRIDE);
    k_outpos<<<((NS - 1) * STRIDE + 255) / 256, 256, 0, stream>>>(perm, pos, outpos0, STRIDE, (NS - 1) * STRIDE);

    k_step<1, 0><<<MAXT, 256, 0, stream>>>(x, carryA, Wt, bias, pb, tilef, outpos0, perm, NG);
    for (int t = 1; t < NS - 1; ++t) {
      const unsigned short* s = (t & 1) ? carryA : carryB;
      unsigned short* d = (t & 1) ? carryB : carryA;
      k_step<0, 0><<<MAXT, 256, 0, stream>>>(s, d, Wt, bias,
          pb + t * (NG + 1), tilef + t * MAXT, perm + t * STRIDE, nullptr, NG);
    }
    k_step<0, 1><<<MAXT, 256, 0, stream>>>(carryA, d_out, Wt, bias,
        pb + (NS - 1) * (NG + 1), tilef + (NS - 1) * MAXT, perm + (NS - 1) * STRIDE, nullptr, NG);
  }
}